// Round 2
// baseline (445.279 us; speedup 1.0000x reference)
//
#include <hip/hip_runtime.h>

// BSplineLayer: piecewise-linear spline eval, branch-free segment search.
// u: [4096,64,256] f32 (channel fastest), knots/coefs: [256,64] f32.
//
// R1 change vs R0: replaced the while-loop corrector (serialized dependent
// ds_read chains, ~4k cyc/wave-iter) with a BRANCH-FREE predictor+-1 select:
//   j = clamp((x-kmin)*scale)  -> read k[j-1..j+2] from guard-padded LDS
//   (no address clamps -> compiler merges to ds_read2_b32, batches all reads)
//   -> select segment among {j-1,j,j+1} in registers -> one ds_read2 for c.
// Correct for any knots where the linear guess is within +-1 segment
// (exact for this module's linspace knots incl. fp rounding; tie/boundary
// semantics match searchsorted side='left' + clip(idx-1,0,62)).
//
//  - Block owns 64 channels; knots staged with lo/hi guard slots so j-1/j+2
//    never need clamping. Stride 67 (odd) spreads banks.
//  - float4 load/store, 2 rows/thread for MLP; 16 lanes x 16B = 256B
//    contiguous per load instruction.
//  - 1024 blocks, ~35KB LDS -> 4 blocks/CU = 16 waves/CU.

#define EPS 1e-6f
#define NCH_GROUP 64
#define KSTRIDE 67         // 66 used slots (+2 guards) padded to odd
#define NGROUPS 4
#define BLOCKS_PER_GROUP 256

__global__ __launch_bounds__(256) void bspline_kernel(
    const float* __restrict__ u, const float* __restrict__ knots,
    const float* __restrict__ coefs, float* __restrict__ out, int n_rows)
{
    // sK[c][0] = k[0] (guard), sK[c][1+i] = k[i], sK[c][65] = k[63] (guard)
    __shared__ float sK[NCH_GROUP * KSTRIDE];
    __shared__ float sC[NCH_GROUP * KSTRIDE];

    const int t = threadIdx.x;
    const int g = blockIdx.x & (NGROUPS - 1);
    const int b = blockIdx.x >> 2;

    const float* gk = knots + (size_t)g * NCH_GROUP * 64;
    const float* gc = coefs + (size_t)g * NCH_GROUP * 64;
    for (int i = t; i < NCH_GROUP * 64; i += 256) {
        int c = i >> 6;
        int k = i & 63;
        float kv = gk[i];
        sK[c * KSTRIDE + 1 + k] = kv;
        sC[c * KSTRIDE + k] = gc[i];
        if (k == 0)  sK[c * KSTRIDE + 0]  = kv;   // lo guard
        if (k == 63) sK[c * KSTRIDE + 65] = kv;   // hi guard
    }
    __syncthreads();

    const int col4 = t & 15;
    const int rsub = t >> 4;
    const int lc = col4 * 4;

    float kmin[4], scale[4];
    int kbase[4], cbase[4];
#pragma unroll
    for (int cc = 0; cc < 4; ++cc) {
        kbase[cc] = (lc + cc) * KSTRIDE;
        cbase[cc] = (lc + cc) * KSTRIDE;
        float klo = sK[kbase[cc] + 1];
        float khi = sK[kbase[cc] + 64];
        kmin[cc] = klo;
        scale[cc] = 63.0f * __builtin_amdgcn_rcpf(khi - klo);
    }

    const float4* u4 = (const float4*)u;
    float4* o4 = (float4*)out;
    const int colbase = g * 16 + col4;
    const int ntiles = n_rows / 32;          // 32 rows per block-iteration

    for (int rt = b; rt < ntiles; rt += BLOCKS_PER_GROUP) {
        size_t i0 = ((size_t)(rt * 32 + rsub)) * 64 + colbase;
        size_t i1 = i0 + (size_t)16 * 64;
        float4 xa = u4[i0];
        float4 xb = u4[i1];

        float x[8], km1[8], k0[8], k1[8], k2[8], c0[8], c1[8];
        int j[8];
        x[0] = xa.x; x[1] = xa.y; x[2] = xa.z; x[3] = xa.w;
        x[4] = xb.x; x[5] = xb.y; x[6] = xb.z; x[7] = xb.w;

        // Phase 1: predict segment (no memory)
#pragma unroll
        for (int e = 0; e < 8; ++e) {
            int cc = e & 3;
            float xs = (x[e] - kmin[cc]) * scale[cc];
            int jj = (int)xs;
            j[e] = max(0, min(62, jj));
        }
        // Phase 2: batched k reads (guarded layout: indices j..j+3 in [0,65])
#pragma unroll
        for (int e = 0; e < 8; ++e) {
            const float* kp = &sK[kbase[e & 3] + j[e]];
            km1[e] = kp[0];   // k[j-1] (or k[0] guard)
            k0[e]  = kp[1];   // k[j]
            k1[e]  = kp[2];   // k[j+1]
            k2[e]  = kp[3];   // k[j+2] (or k[63] guard)
        }
        // Phase 3: branch-free +-1 correction + segment select
        float K0[8], K1[8];
        int j2[8];
#pragma unroll
        for (int e = 0; e < 8; ++e) {
            bool dn = (k0[e] >= x[e]) & (j[e] > 0);
            bool up = (k1[e] <  x[e]) & (j[e] < 62);
            j2[e] = j[e] + (up ? 1 : 0) - (dn ? 1 : 0);
            K0[e] = dn ? km1[e] : (up ? k1[e] : k0[e]);
            K1[e] = dn ? k0[e]  : (up ? k2[e] : k1[e]);
        }
        // Phase 4: batched c reads
#pragma unroll
        for (int e = 0; e < 8; ++e) {
            const float* cp = &sC[cbase[e & 3] + j2[e]];
            c0[e] = cp[0];
            c1[e] = cp[1];
        }
        // Phase 5: interpolate
        float r[8];
#pragma unroll
        for (int e = 0; e < 8; ++e) {
            float tt = (x[e] - K0[e]) * __builtin_amdgcn_rcpf(K1[e] - K0[e] + EPS);
            r[e] = fmaf(tt, c1[e] - c0[e], c0[e]);
        }

        float4 ra, rb;
        ra.x = r[0]; ra.y = r[1]; ra.z = r[2]; ra.w = r[3];
        rb.x = r[4]; rb.y = r[5]; rb.z = r[6]; rb.w = r[7];
        o4[i0] = ra;
        o4[i1] = rb;
    }
}

extern "C" void kernel_launch(void* const* d_in, const int* in_sizes, int n_in,
                              void* d_out, int out_size, void* d_ws, size_t ws_size,
                              hipStream_t stream) {
    const float* u     = (const float*)d_in[0];
    const float* knots = (const float*)d_in[1];
    const float* coefs = (const float*)d_in[2];
    float* out = (float*)d_out;

    int n_rows = in_sizes[0] / 256;   // 262144 rows of 256 channels

    dim3 grid(NGROUPS * BLOCKS_PER_GROUP);
    dim3 block(256);
    bspline_kernel<<<grid, block, 0, stream>>>(u, knots, coefs, out, n_rows);
}